// Round 4
// baseline (173.154 us; speedup 1.0000x reference)
//
#include <hip/hip_runtime.h>
#include <math.h>

// NaiveDFTQNN: 25-wire state vector, DIM = 2^25.
// out = (cos(theta[0]/2)/||f||) * (tensor product of 12 Givens rotations) * f
// Pair j (j=0..11) acts on little-endian element bits (2j+1, 2j), angle theta[11-j]/2:
//   v=01 (bit 2j set):   n01 = c*a01 - s*a10
//   v=10 (bit 2j+1 set): n10 = s*a01 + c*a10 ;  v=00,11 untouched.
// Bit 24 (wire 0) is a spectator (RX folds into the scalar).
//
// 3 coalesced passes (every wave-load/store >= 1KB contiguous; 64B-granule
// power-of-2-stride gathers measured ~2 TB/s vs ~10 TB/s contiguous):
//   P1: j0..j6  (bits 0..13), in->out, + sum-of-squares partials. Contiguous tile.
//   P2: j7..j9  (bits 14..19), in place. 64 h-combos x 256-float payload.
//   P3: j10,j11 (bits 20..23) + scale, in place. 16 h-combos x 1024-float payload.
// All tiles 64KB LDS, 1024 threads, 4 float4/thread -> 2 blocks/CU, conflict-free
// linear LDS (lane = slot bits 0..5 everywhere).

static __device__ __forceinline__ void rot4(float4& a, float4& b, float c, float s) {
    float4 na, nb;
    na.x = c*a.x - s*b.x;  nb.x = s*a.x + c*b.x;
    na.y = c*a.y - s*b.y;  nb.y = s*a.y + c*b.y;
    na.z = c*a.z - s*b.z;  nb.z = s*a.z + c*b.z;
    na.w = c*a.w - s*b.w;  nb.w = s*a.w + c*b.w;
    a = na; b = nb;
}

static __device__ __forceinline__ float4 shflx4(float4 v, int m) {
    float4 r;
    r.x = __shfl_xor(v.x, m, 64);
    r.y = __shfl_xor(v.y, m, 64);
    r.z = __shfl_xor(v.z, m, 64);
    r.w = __shfl_xor(v.w, m, 64);
    return r;
}

// Givens pair on lane bits (sh+1, sh): pv = (lane>>sh)&3; lanes 01/10 exchange with
// partner lane^(3<<sh). Branchless per-lane (cl,sl).
static __device__ __forceinline__ void rotshfl(float4* f, int sh, float c, float s, int lane) {
    const int pv = (lane >> sh) & 3;
    const bool act = (pv == 1) || (pv == 2);
    const float cl = act ? c : 1.0f;
    const float sl = act ? ((pv == 1) ? -s : s) : 0.0f;
    const int m = 3 << sh;
#pragma unroll
    for (int k = 0; k < 4; ++k) {
        float4 p = shflx4(f[k], m);
        float4 n;
        n.x = fmaf(sl, p.x, cl * f[k].x);
        n.y = fmaf(sl, p.y, cl * f[k].y);
        n.z = fmaf(sl, p.z, cl * f[k].z);
        n.w = fmaf(sl, p.w, cl * f[k].w);
        f[k] = n;
    }
}

// ---------------- P1: pairs j0..j6 (el bits 0..13), in -> out, + partials ----------
// Tile = contiguous 16384 floats (4096 quads, slot bits 0..11 = el bits 2..13).
// j0: float4 components (el bits 1,0). j1,j2,j3: lane shuffles (slot bits 1,0/3,2/5,4).
// j4: slot bits 7,6 (LDS trip 1). j5: slot bits 9,8 (LDS trip 2). j6: slot bits 11,10 (k regs).
__global__ __launch_bounds__(1024, 8) void qnn_p1(const float* __restrict__ in,
                                                  const float* __restrict__ theta,
                                                  float* __restrict__ out,
                                                  double* __restrict__ partials) {
    __shared__ __align__(16) float4 lds[4096];
    __shared__ double red[16];
    const int t = threadIdx.x, lane = t & 63;
    const long gfb = (long)blockIdx.x << 12;   // quad base

    // pair j -> theta[11-j]
    float c0,s0,c1,s1,c2,s2,c3,s3,c4,s4,c5,s5,c6,s6;
    { float th;
      th=0.5f*theta[11]; c0=cosf(th); s0=sinf(th);
      th=0.5f*theta[10]; c1=cosf(th); s1=sinf(th);
      th=0.5f*theta[9];  c2=cosf(th); s2=sinf(th);
      th=0.5f*theta[8];  c3=cosf(th); s3=sinf(th);
      th=0.5f*theta[7];  c4=cosf(th); s4=sinf(th);
      th=0.5f*theta[6];  c5=cosf(th); s5=sinf(th);
      th=0.5f*theta[5];  c6=cosf(th); s6=sinf(th); }

    float4 f[4];
    double acc = 0.0;
#pragma unroll
    for (int k = 0; k < 4; ++k) {
        f[k] = *(const float4*)(in + ((gfb + k*1024 + t) << 2));
        acc += (double)f[k].x*f[k].x + (double)f[k].y*f[k].y
             + (double)f[k].z*f[k].z + (double)f[k].w*f[k].w;
    }
    // j0: el bits (1,0) = components (y,z)
#pragma unroll
    for (int k = 0; k < 4; ++k) {
        float ny = c0*f[k].y - s0*f[k].z;
        float nz = s0*f[k].y + c0*f[k].z;
        f[k].y = ny; f[k].z = nz;
    }
    rotshfl(f, 0, c1, s1, lane);     // j1: slot bits 1,0
    rotshfl(f, 2, c2, s2, lane);     // j2: slot bits 3,2
    rotshfl(f, 4, c3, s3, lane);     // j3: slot bits 5,4
    rot4(f[1], f[2], c6, s6);        // j6: slot bits 11,10 = k

#pragma unroll
    for (int k = 0; k < 4; ++k) lds[k*1024 + t] = f[k];
    __syncthreads();
    {   // j4: slot bits 7,6
        const int sb = ((t >> 6) << 8) | (t & 63);
#pragma unroll
        for (int b = 0; b < 4; ++b) f[b] = lds[sb | (b << 6)];
        rot4(f[1], f[2], c4, s4);
#pragma unroll
        for (int b = 0; b < 4; ++b) lds[sb | (b << 6)] = f[b];
    }
    __syncthreads();
    {   // j5: slot bits 9,8 + store
        const int sb = ((t >> 8) << 10) | (t & 255);
#pragma unroll
        for (int b = 0; b < 4; ++b) f[b] = lds[sb | (b << 8)];
        rot4(f[1], f[2], c5, s5);
#pragma unroll
        for (int b = 0; b < 4; ++b)
            *(float4*)(out + ((gfb + (sb | (b << 8))) << 2)) = f[b];
    }
    // deterministic sum-of-squares partial
#pragma unroll
    for (int off = 32; off > 0; off >>= 1) acc += __shfl_down(acc, off, 64);
    if (lane == 0) red[t >> 6] = acc;
    __syncthreads();
    if (t == 0) {
        double s = 0.0;
#pragma unroll
        for (int i = 0; i < 16; ++i) s += red[i];
        partials[blockIdx.x] = s;
    }
}

// ---------------- Norm: 2048 partials -> scale = cos(theta[0]/2)/sqrt(sum) ---------
__global__ void qnn_norm(const double* __restrict__ partials,
                         const float* __restrict__ theta,
                         double* __restrict__ scale) {
    __shared__ double w[4];
    const int t = threadIdx.x;
    double acc = 0.0;
    for (int i = t; i < 2048; i += 256) acc += partials[i];
#pragma unroll
    for (int off = 32; off > 0; off >>= 1) acc += __shfl_down(acc, off, 64);
    if ((t & 63) == 0) w[t >> 6] = acc;
    __syncthreads();
    if (t == 0) {
        double tot = w[0] + w[1] + w[2] + w[3];
        *scale = (double)cosf(0.5f * theta[0]) / sqrt(tot);
    }
}

// ---------------- P2: pairs j7..j9 (el bits 14..19), in place ----------------------
// Tile: payload = el bits 0..7 (64 quads, slot bits 0..5), h = el bits 14..19
// (slot bits 6..11). Block covers el bits 8..13 (blkmid, quad bits 6..11) and
// 20..24 (blkhi, quad bits 18..22).
// j7 = slot bits 7,6 (k regs); j8 = slot bits 9,8 (trip 1); j9 = slot bits 11,10 (trip 2).
__global__ __launch_bounds__(1024, 8) void qnn_p2(float* __restrict__ buf,
                                                  const float* __restrict__ theta) {
    __shared__ __align__(16) float4 lds[4096];
    const int t = threadIdx.x, lane = t & 63, w = t >> 6;
    const int bid = blockIdx.x;
    const int blkhi = bid >> 6, blkmid = bid & 63;
    const long base = ((long)blkhi << 18) | ((long)blkmid << 6);   // quad units

    float c7,s7,c8,s8,c9,s9;
    { float th;
      th=0.5f*theta[4]; c7=cosf(th); s7=sinf(th);
      th=0.5f*theta[3]; c8=cosf(th); s8=sinf(th);
      th=0.5f*theta[2]; c9=cosf(th); s9=sinf(th); }

    float4 f[4];
#pragma unroll
    for (int k = 0; k < 4; ++k) {
        const int slot = ((w >> 2) << 10) | ((w & 3) << 8) | (k << 6) | lane;
        f[k] = *(const float4*)(buf + ((base + ((long)(slot >> 6) << 12) + (slot & 63)) << 2));
    }
    rot4(f[1], f[2], c7, s7);          // j7 = slot bits 7,6 = k
#pragma unroll
    for (int k = 0; k < 4; ++k) {
        const int slot = ((w >> 2) << 10) | ((w & 3) << 8) | (k << 6) | lane;
        lds[slot] = f[k];
    }
    __syncthreads();
    {   // j8 = slot bits 9,8
#pragma unroll
        for (int b = 0; b < 4; ++b) {
            const int slot = ((w >> 2) << 10) | (b << 8) | ((w & 3) << 6) | lane;
            f[b] = lds[slot];
        }
        rot4(f[1], f[2], c8, s8);
#pragma unroll
        for (int b = 0; b < 4; ++b) {
            const int slot = ((w >> 2) << 10) | (b << 8) | ((w & 3) << 6) | lane;
            lds[slot] = f[b];
        }
    }
    __syncthreads();
    {   // j9 = slot bits 11,10 + store
#pragma unroll
        for (int b = 0; b < 4; ++b) {
            const int slot = (b << 10) | ((w >> 2) << 8) | ((w & 3) << 6) | lane;
            f[b] = lds[slot];
        }
        rot4(f[1], f[2], c9, s9);
#pragma unroll
        for (int b = 0; b < 4; ++b) {
            const int slot = (b << 10) | ((w >> 2) << 8) | ((w & 3) << 6) | lane;
            *(float4*)(buf + ((base + ((long)(slot >> 6) << 12) + (slot & 63)) << 2)) = f[b];
        }
    }
}

// ---------------- P3: pairs j10,j11 (el bits 20..23) + scale, in place -------------
// Tile: payload = el bits 0..9 (256 quads, slot bits 0..7), h = el bits 20..23
// (slot bits 8..11 -> quad bits 18..21). Block covers el bits 10..19 (blkmid,
// quad bits 8..17) and bit 24 (quad bit 22).
// j10 = slot bits 9,8 (k regs); j11 = slot bits 11,10 (1 LDS trip).
__global__ __launch_bounds__(1024, 8) void qnn_p3(float* __restrict__ buf,
                                                  const float* __restrict__ theta,
                                                  const double* __restrict__ scale) {
    __shared__ __align__(16) float4 lds[4096];
    const int t = threadIdx.x, lane = t & 63, w = t >> 6;
    const int bid = blockIdx.x;
    const int b24 = bid >> 10, blkmid = bid & 1023;
    const long base = ((long)b24 << 22) | ((long)blkmid << 8);     // quad units (b24 -> quad bit 22)

    float c10,s10,c11,s11;
    { float th;
      th=0.5f*theta[1]; c10=cosf(th); s10=sinf(th);
      th=0.5f*theta[0]; c11=cosf(th); s11=sinf(th); }
    const float sc = (float)(*scale);

    float4 f[4];
#pragma unroll
    for (int k = 0; k < 4; ++k) {
        const int slot = ((w >> 2) << 10) | (k << 8) | ((w & 3) << 6) | lane;
        f[k] = *(const float4*)(buf + ((base + ((long)(slot >> 8) << 18) + (slot & 255)) << 2));
    }
    rot4(f[1], f[2], c10, s10);        // j10 = slot bits 9,8 = k
#pragma unroll
    for (int k = 0; k < 4; ++k) {
        const int slot = ((w >> 2) << 10) | (k << 8) | ((w & 3) << 6) | lane;
        lds[slot] = f[k];
    }
    __syncthreads();
    {   // j11 = slot bits 11,10 + scale + store
#pragma unroll
        for (int b = 0; b < 4; ++b) {
            const int slot = (b << 10) | ((w >> 2) << 8) | ((w & 3) << 6) | lane;
            f[b] = lds[slot];
        }
        rot4(f[1], f[2], c11, s11);
#pragma unroll
        for (int b = 0; b < 4; ++b) {
            const int slot = (b << 10) | ((w >> 2) << 8) | ((w & 3) << 6) | lane;
            float4 v = f[b];
            v.x *= sc; v.y *= sc; v.z *= sc; v.w *= sc;
            *(float4*)(buf + ((base + ((long)(slot >> 8) << 18) + (slot & 255)) << 2)) = v;
        }
    }
}

extern "C" void kernel_launch(void* const* d_in, const int* in_sizes, int n_in,
                              void* d_out, int out_size, void* d_ws, size_t ws_size,
                              hipStream_t stream) {
    const float* in = (const float*)d_in[0];      // feature, 2^25 f32
    const float* theta = (const float*)d_in[1];   // 13 f32
    float* out = (float*)d_out;                   // 2^25 f32
    double* part = (double*)d_ws;                 // 2048 partials + 1 scale
    double* scale = part + 2048;

    qnn_p1<<<2048, 1024, 0, stream>>>(in, theta, out, part);
    qnn_norm<<<1, 256, 0, stream>>>(part, theta, scale);
    qnn_p2<<<2048, 1024, 0, stream>>>(out, theta);
    qnn_p3<<<2048, 1024, 0, stream>>>(out, theta, scale);
}

// Round 6
// 122.235 us; speedup vs baseline: 1.4166x; 1.4166x over previous
//
#include <hip/hip_runtime.h>
#include <math.h>

// NaiveDFTQNN: 25-wire state vector, DIM = 2^25.
// out = (cos(theta[0]/2)/||f||) * (tensor product of 12 Givens rotations) * f
// Pair j (j=0..11) acts on little-endian element bits (2j+1, 2j), angle theta[11-j]/2:
//   v=01 (bit 2j set):   n01 = c*a01 - s*a10
//   v=10 (bit 2j+1 set): n10 = s*a01 + c*a10 ;  v=00,11 untouched.
// Bit 24 (wire 0) is a spectator (RX folds into the scalar).
//
// 2 big passes (512 MB fabric traffic, the 2-pass minimum):
//   P1 (qnn_p1):   j0..j6 (bits 0..13), in->out, contiguous, + sumsq partials.
//                  NT-loads `in` (no IC allocate: no intra-iteration reuse).
//   P2' (qnn_high): j7..j11 (bits 14..23) + scale, out in place, 128 KB LDS tile
//                  (1024 H x 32-float payload -> 128 B granules = full L2 lines).
//                  NT-stores final result (nobody re-reads it).
// IC then holds only the P1->P2' intermediate (128 MB of 256 MB IC).

typedef float f32x4 __attribute__((ext_vector_type(4)));

static __device__ __forceinline__ float4 nt_load4(const float* p) {
    f32x4 v = __builtin_nontemporal_load((const f32x4*)p);
    return *(float4*)&v;
}
static __device__ __forceinline__ void nt_store4(float* p, float4 v) {
    __builtin_nontemporal_store(*(f32x4*)&v, (f32x4*)p);
}

static __device__ __forceinline__ void rot4(float4& a, float4& b, float c, float s) {
    float4 na, nb;
    na.x = c*a.x - s*b.x;  nb.x = s*a.x + c*b.x;
    na.y = c*a.y - s*b.y;  nb.y = s*a.y + c*b.y;
    na.z = c*a.z - s*b.z;  nb.z = s*a.z + c*b.z;
    na.w = c*a.w - s*b.w;  nb.w = s*a.w + c*b.w;
    a = na; b = nb;
}

static __device__ __forceinline__ float4 shflx4(float4 v, int m) {
    float4 r;
    r.x = __shfl_xor(v.x, m, 64);
    r.y = __shfl_xor(v.y, m, 64);
    r.z = __shfl_xor(v.z, m, 64);
    r.w = __shfl_xor(v.w, m, 64);
    return r;
}

// Givens pair on lane bits (sh+1, sh), over NR float4 regs. Branchless per-lane (cl,sl).
template <int NR>
static __device__ __forceinline__ void rotshfl(float4* f, int sh, float c, float s, int lane) {
    const int pv = (lane >> sh) & 3;
    const bool act = (pv == 1) || (pv == 2);
    const float cl = act ? c : 1.0f;
    const float sl = act ? ((pv == 1) ? -s : s) : 0.0f;
    const int m = 3 << sh;
#pragma unroll
    for (int k = 0; k < NR; ++k) {
        float4 p = shflx4(f[k], m);
        float4 n;
        n.x = fmaf(sl, p.x, cl * f[k].x);
        n.y = fmaf(sl, p.y, cl * f[k].y);
        n.z = fmaf(sl, p.z, cl * f[k].z);
        n.w = fmaf(sl, p.w, cl * f[k].w);
        f[k] = n;
    }
}

// ---------------- P1: pairs j0..j6 (el bits 0..13), in -> out, + partials ----------
// Tile = contiguous 16384 floats (4096 quads, slot bits 0..11 = el bits 2..13).
// j0: float4 components. j1,j2,j3: lane shuffles. j4: slot bits 7,6 (LDS trip 1).
// j5: slot bits 9,8 (LDS trip 2). j6: slot bits 11,10 (k regs).
__global__ __launch_bounds__(1024, 8) void qnn_p1(const float* __restrict__ in,
                                                  const float* __restrict__ theta,
                                                  float* __restrict__ out,
                                                  double* __restrict__ partials) {
    __shared__ __align__(16) float4 lds[4096];
    __shared__ double red[16];
    const int t = threadIdx.x, lane = t & 63;
    const long gfb = (long)blockIdx.x << 12;   // quad base

    float c0,s0,c1,s1,c2,s2,c3,s3,c4,s4,c5,s5,c6,s6;
    { float th;
      th=0.5f*theta[11]; c0=cosf(th); s0=sinf(th);
      th=0.5f*theta[10]; c1=cosf(th); s1=sinf(th);
      th=0.5f*theta[9];  c2=cosf(th); s2=sinf(th);
      th=0.5f*theta[8];  c3=cosf(th); s3=sinf(th);
      th=0.5f*theta[7];  c4=cosf(th); s4=sinf(th);
      th=0.5f*theta[6];  c5=cosf(th); s5=sinf(th);
      th=0.5f*theta[5];  c6=cosf(th); s6=sinf(th); }

    float4 f[4];
    double acc = 0.0;
#pragma unroll
    for (int k = 0; k < 4; ++k) {
        f[k] = nt_load4(in + ((gfb + k*1024 + t) << 2));
        acc += (double)f[k].x*f[k].x + (double)f[k].y*f[k].y
             + (double)f[k].z*f[k].z + (double)f[k].w*f[k].w;
    }
    // j0: el bits (1,0) = components (y,z)
#pragma unroll
    for (int k = 0; k < 4; ++k) {
        float ny = c0*f[k].y - s0*f[k].z;
        float nz = s0*f[k].y + c0*f[k].z;
        f[k].y = ny; f[k].z = nz;
    }
    rotshfl<4>(f, 0, c1, s1, lane);  // j1: slot bits 1,0
    rotshfl<4>(f, 2, c2, s2, lane);  // j2: slot bits 3,2
    rotshfl<4>(f, 4, c3, s3, lane);  // j3: slot bits 5,4
    rot4(f[1], f[2], c6, s6);        // j6: slot bits 11,10 = k

#pragma unroll
    for (int k = 0; k < 4; ++k) lds[k*1024 + t] = f[k];
    __syncthreads();
    {   // j4: slot bits 7,6
        const int sb = ((t >> 6) << 8) | (t & 63);
#pragma unroll
        for (int b = 0; b < 4; ++b) f[b] = lds[sb | (b << 6)];
        rot4(f[1], f[2], c4, s4);
#pragma unroll
        for (int b = 0; b < 4; ++b) lds[sb | (b << 6)] = f[b];
    }
    __syncthreads();
    {   // j5: slot bits 9,8 + store (regular store: want IC-resident for P2')
        const int sb = ((t >> 8) << 10) | (t & 255);
#pragma unroll
        for (int b = 0; b < 4; ++b) f[b] = lds[sb | (b << 8)];
        rot4(f[1], f[2], c5, s5);
#pragma unroll
        for (int b = 0; b < 4; ++b)
            *(float4*)(out + ((gfb + (sb | (b << 8))) << 2)) = f[b];
    }
    // deterministic sum-of-squares partial
#pragma unroll
    for (int off = 32; off > 0; off >>= 1) acc += __shfl_down(acc, off, 64);
    if (lane == 0) red[t >> 6] = acc;
    __syncthreads();
    if (t == 0) {
        double s = 0.0;
#pragma unroll
        for (int i = 0; i < 16; ++i) s += red[i];
        partials[blockIdx.x] = s;
    }
}

// ---------------- Norm: 2048 partials -> scale = cos(theta[0]/2)/sqrt(sum) ---------
__global__ void qnn_norm(const double* __restrict__ partials,
                         const float* __restrict__ theta,
                         double* __restrict__ scale) {
    __shared__ double w[4];
    const int t = threadIdx.x;
    double acc = 0.0;
    for (int i = t; i < 2048; i += 256) acc += partials[i];
#pragma unroll
    for (int off = 32; off > 0; off >>= 1) acc += __shfl_down(acc, off, 64);
    if ((t & 63) == 0) w[t >> 6] = acc;
    __syncthreads();
    if (t == 0) {
        double tot = w[0] + w[1] + w[2] + w[3];
        *scale = (double)cosf(0.5f * theta[0]) / sqrt(tot);
    }
}

// ---------------- P2': pairs j7..j11 (el bits 14..23) + scale, in place ------------
// Tile: 1024 H-combos (el bits 14..23) x 32-float payload (el bits 0..4) = 128 KB.
// Element addr = b24<<24 | H<<14 | mid<<5 | p5;  block id = b24<<9 | mid (1024 blocks).
// Tile slot s (13 bits) = H<<3 | pq  (pq = quad-in-granule, el bits 2..4).
// Global quad = b24<<22 | H<<12 | mid<<3 | pq -> every wave instruction touches
// 8 x 128 B full lines (granule 128 B, stride 64 KB).
// Gate bits on s: j7=(4,3) j8=(6,5) j9=(8,7) j10=(10,9) j11=(12,11).
// Schedule: load (s = k<<10 | w<<6 | lane): j7 via lane shuffles, j11 via k regs;
// trip1 (s = (lane>>5)<<12 | w<<8 | b<<5 | lane&31): j8 via b regs;
// trip2 (s = (w>>1)<<10 | b<<7 | (w&1)<<6 | lane): j9 via b regs;
// final (s = (w>>3)<<12 | k<<9 | (w&7)<<6 | lane): j10 via k regs + scale + NT store.
// All mappings keep s&7 == lane&7 -> conflict-free b128 LDS.
__global__ __launch_bounds__(1024, 4) void qnn_high(float* __restrict__ buf,
                                                    const float* __restrict__ theta,
                                                    const double* __restrict__ scale) {
    __shared__ __align__(16) float4 lds[8192];   // 128 KB
    const int t = threadIdx.x, lane = t & 63, w = t >> 6;
    const int bid = blockIdx.x;
    const int b24 = bid >> 9, mid = bid & 511;
    const long gq = ((long)b24 << 22) | ((long)mid << 3);   // quad base

    float c7,s7,c8,s8,c9,s9,c10,s10,c11,s11;
    { float th;
      th=0.5f*theta[4]; c7 =cosf(th); s7 =sinf(th);
      th=0.5f*theta[3]; c8 =cosf(th); s8 =sinf(th);
      th=0.5f*theta[2]; c9 =cosf(th); s9 =sinf(th);
      th=0.5f*theta[1]; c10=cosf(th); s10=sinf(th);
      th=0.5f*theta[0]; c11=cosf(th); s11=sinf(th); }
    const float sc = (float)(*scale);

    float4 f[8];
    // ---- load: s = k<<10 | w<<6 | lane ----
#pragma unroll
    for (int k = 0; k < 8; ++k) {
        const int s_ = (k << 10) | t;
        f[k] = *(const float4*)(buf + ((gq | ((long)(s_ >> 3) << 12) | (s_ & 7)) << 2));
    }
    rotshfl<8>(f, 3, c7, s7, lane);          // j7: s bits 4,3 = lane bits 4,3
    rot4(f[2], f[4], c11, s11);              // j11: s bits 12,11 = k bits 2,1
    rot4(f[3], f[5], c11, s11);
#pragma unroll
    for (int k = 0; k < 8; ++k) lds[(k << 10) | t] = f[k];
    __syncthreads();

    {   // ---- trip1: j8 (s bits 6,5 = b bits 1,0) ----
        const int base = ((lane >> 5) << 12) | (w << 8) | (lane & 31);
#pragma unroll
        for (int b = 0; b < 8; ++b) f[b] = lds[base | (b << 5)];
        rot4(f[1], f[2], c8, s8);
        rot4(f[5], f[6], c8, s8);
#pragma unroll
        for (int b = 0; b < 8; ++b) lds[base | (b << 5)] = f[b];
    }
    __syncthreads();

    {   // ---- trip2: j9 (s bits 8,7 = b bits 1,0) ----
        const int base = ((w >> 1) << 10) | ((w & 1) << 6) | lane;
#pragma unroll
        for (int b = 0; b < 8; ++b) f[b] = lds[base | (b << 7)];
        rot4(f[1], f[2], c9, s9);
        rot4(f[5], f[6], c9, s9);
#pragma unroll
        for (int b = 0; b < 8; ++b) lds[base | (b << 7)] = f[b];
    }
    __syncthreads();

    {   // ---- final: j10 (s bits 10,9 = k bits 1,0) + scale + NT store ----
        const int base = ((w >> 3) << 12) | ((w & 7) << 6) | lane;
#pragma unroll
        for (int k = 0; k < 8; ++k) f[k] = lds[base | (k << 9)];
        rot4(f[1], f[2], c10, s10);
        rot4(f[5], f[6], c10, s10);
#pragma unroll
        for (int k = 0; k < 8; ++k) {
            const int s_ = base | (k << 9);
            float4 v = f[k];
            v.x *= sc; v.y *= sc; v.z *= sc; v.w *= sc;
            nt_store4(buf + ((gq | ((long)(s_ >> 3) << 12) | (s_ & 7)) << 2), v);
        }
    }
}

extern "C" void kernel_launch(void* const* d_in, const int* in_sizes, int n_in,
                              void* d_out, int out_size, void* d_ws, size_t ws_size,
                              hipStream_t stream) {
    const float* in = (const float*)d_in[0];      // feature, 2^25 f32
    const float* theta = (const float*)d_in[1];   // 13 f32
    float* out = (float*)d_out;                   // 2^25 f32
    double* part = (double*)d_ws;                 // 2048 partials + 1 scale
    double* scale = part + 2048;

    qnn_p1<<<2048, 1024, 0, stream>>>(in, theta, out, part);
    qnn_norm<<<1, 256, 0, stream>>>(part, theta, scale);
    qnn_high<<<1024, 1024, 0, stream>>>(out, theta, scale);
}